// Round 1
// baseline (1024.213 us; speedup 1.0000x reference)
//
#include <hip/hip_runtime.h>

typedef unsigned short u16;
typedef __attribute__((ext_vector_type(8))) short bf16x8;
typedef __attribute__((ext_vector_type(4))) float f32x4;

#define D_MODEL 1024
#define T_SEQ   2048
#define NB      4
#define NH      16
#define DKH     64

__device__ __forceinline__ u16 f2bf(float x) {
  union { float f; unsigned u; } v; v.f = x;
  unsigned r = v.u + 0x7fffu + ((v.u >> 16) & 1u);
  return (u16)(r >> 16);
}
__device__ __forceinline__ unsigned pack2(float a, float b) {
  return (unsigned)f2bf(a) | ((unsigned)f2bf(b) << 16);
}

// ---------------- cast fp32 -> bf16 (n multiple of 4) ----------------
__global__ void cast_f32_bf16(const float* __restrict__ src, u16* __restrict__ dst, int n) {
  int i = ((int)blockIdx.x * 256 + (int)threadIdx.x) * 4;
  if (i >= n) return;
  float4 v = *(const float4*)(src + i);
  uint2 o; o.x = pack2(v.x, v.y); o.y = pack2(v.z, v.w);
  *(uint2*)(dst + i) = o;
}

// ---------------- GEMM: C[M,N] = A[M,K] @ W[N,K]^T + bias ----------------
// A: bf16 (A_F32=0) or fp32 (A_F32=1, converted during staging). W: bf16. bias: fp32.
// OUT_BF16: store bf16, else fp32. Tiles: 128x128, BK=64, 256 thr (4 waves, 2x2).
#define LDSK 72   // padded LDS row stride (bf16 elems); 144B rows, 16B aligned

template<int OUT_BF16, int A_F32>
__global__ __launch_bounds__(256) void gemm_nt(const void* __restrict__ Ap,
                                               const u16* __restrict__ W,
                                               const float* __restrict__ bias,
                                               void* __restrict__ Cp,
                                               int M, int N, int K) {
  __shared__ __align__(16) u16 As[128 * LDSK];
  __shared__ __align__(16) u16 Bs[128 * LDSK];
  const int tid = threadIdx.x;
  const int w = tid >> 6, lane = tid & 63;
  const int wm = w & 1, wn = w >> 1;
  const int l15 = lane & 15, quad = lane >> 4;
  const int m0 = blockIdx.x * 128, n0 = blockIdx.y * 128;
  const int srow = tid >> 3;        // 0..31
  const int scol = (tid & 7) * 8;   // 0..56

  f32x4 zero4 = {0.f, 0.f, 0.f, 0.f};
  f32x4 acc[4][4];
#pragma unroll
  for (int i = 0; i < 4; ++i)
#pragma unroll
    for (int j = 0; j < 4; ++j) acc[i][j] = zero4;

  for (int kb = 0; kb < K; kb += 64) {
    uint4 ra[4], rb[4];
    if (A_F32) {
      const float* Af = (const float*)Ap;
#pragma unroll
      for (int r = 0; r < 4; ++r) {
        const float* p = Af + (size_t)(m0 + r * 32 + srow) * K + kb + scol;
        float4 x = *(const float4*)p;
        float4 y = *(const float4*)(p + 4);
        ra[r].x = pack2(x.x, x.y); ra[r].y = pack2(x.z, x.w);
        ra[r].z = pack2(y.x, y.y); ra[r].w = pack2(y.z, y.w);
      }
    } else {
      const u16* Ab = (const u16*)Ap;
#pragma unroll
      for (int r = 0; r < 4; ++r)
        ra[r] = *(const uint4*)(Ab + (size_t)(m0 + r * 32 + srow) * K + kb + scol);
    }
#pragma unroll
    for (int r = 0; r < 4; ++r)
      rb[r] = *(const uint4*)(W + (size_t)(n0 + r * 32 + srow) * K + kb + scol);

    __syncthreads();   // prev iter's LDS reads done before overwrite
#pragma unroll
    for (int r = 0; r < 4; ++r) {
      *(uint4*)(As + (r * 32 + srow) * LDSK + scol) = ra[r];
      *(uint4*)(Bs + (r * 32 + srow) * LDSK + scol) = rb[r];
    }
    __syncthreads();

#pragma unroll
    for (int ks = 0; ks < 2; ++ks) {
      bf16x8 af[4], bfr[4];
#pragma unroll
      for (int i = 0; i < 4; ++i)
        af[i] = *(const bf16x8*)(As + (wm * 64 + i * 16 + l15) * LDSK + ks * 32 + quad * 8);
#pragma unroll
      for (int i = 0; i < 4; ++i)
        bfr[i] = *(const bf16x8*)(Bs + (wn * 64 + i * 16 + l15) * LDSK + ks * 32 + quad * 8);
#pragma unroll
      for (int mi = 0; mi < 4; ++mi)
#pragma unroll
        for (int ni = 0; ni < 4; ++ni)
          acc[mi][ni] = __builtin_amdgcn_mfma_f32_16x16x32_bf16(af[mi], bfr[ni], acc[mi][ni], 0, 0, 0);
    }
  }

  // epilogue: D[row=quad*4+r][col=lane&15] (verified m90/m91 mapping)
#pragma unroll
  for (int ni = 0; ni < 4; ++ni) {
    int col = n0 + wn * 64 + ni * 16 + l15;
    float bv = bias[col];
#pragma unroll
    for (int mi = 0; mi < 4; ++mi) {
      int row = m0 + wm * 64 + mi * 16 + quad * 4;
#pragma unroll
      for (int r = 0; r < 4; ++r) {
        float vv = acc[mi][ni][r] + bv;
        if (OUT_BF16) ((u16*)Cp)[(size_t)(row + r) * N + col] = f2bf(vv);
        else          ((float*)Cp)[(size_t)(row + r) * N + col] = vv;
      }
    }
  }
}

// ---------------- causal flash attention ----------------
// grid: (T/128 [reversed], NH, NB); block 256 (4 waves). Q-tile 128 rows, K-tile 64.
// Xq/Xk/Xv: bf16 [B*T, 1024], head h = cols [h*64, h*64+64). O: bf16 same layout.
__global__ __launch_bounds__(256) void attn_fwd(const u16* __restrict__ Xq,
                                                const u16* __restrict__ Xk,
                                                const u16* __restrict__ Xv,
                                                u16* __restrict__ O) {
  __shared__ __align__(16) float Ss[128 * 65];  // scores fp32, stride 65
  __shared__ __align__(16) u16   Ps[128 * 72];  // P bf16, stride 72 (16B aligned)
  __shared__ __align__(16) u16   Vt[64 * 72];   // V^T bf16 [d][key]
  __shared__ __align__(16) float al[128];       // per-row rescale factor

  const int qt = (int)gridDim.x - 1 - (int)blockIdx.x;  // heavy tiles first
  const int h = blockIdx.y, b = blockIdx.z;
  const int tid = threadIdx.x;
  const int w = tid >> 6, lane = tid & 63;
  const int l15 = lane & 15, quad = lane >> 4;
  const size_t base = (size_t)b * T_SEQ * D_MODEL;
  const int q0 = qt * 128;
  const int hd = h * DKH;

  // Q fragments (A-operand layout), held for the whole kernel
  bf16x8 aq[2][2];
#pragma unroll
  for (int mi = 0; mi < 2; ++mi)
#pragma unroll
    for (int ks = 0; ks < 2; ++ks)
      aq[mi][ks] = *(const bf16x8*)(Xq + base + (size_t)(q0 + w * 32 + mi * 16 + l15) * D_MODEL
                                    + hd + ks * 32 + quad * 8);

  f32x4 zero4 = {0.f, 0.f, 0.f, 0.f};
  f32x4 o[2][4];
#pragma unroll
  for (int i = 0; i < 2; ++i)
#pragma unroll
    for (int j = 0; j < 4; ++j) o[i][j] = zero4;
  float m_r = -1e30f, l_r = 0.f;

  const int nkt = 2 * qt + 2;
  for (int kt = 0; kt < nkt; ++kt) {
    const int k0 = kt * 64;
    __syncthreads();   // Vt/Ps reuse vs previous iteration's reads

    // stage V^T: Vt[d][key]
    {
      const int d = tid & 63, kb4 = tid >> 6;
      const u16* vp = Xv + base + (size_t)(k0 + kb4) * D_MODEL + hd + d;
#pragma unroll
      for (int i = 0; i < 16; ++i)
        Vt[d * 72 + kb4 + i * 4] = vp[(size_t)(i * 4) * D_MODEL];
    }

    // S = Q K^T  (wave w owns q-rows w*32..w*32+31)
    f32x4 s[2][4];
#pragma unroll
    for (int i = 0; i < 2; ++i)
#pragma unroll
      for (int j = 0; j < 4; ++j) s[i][j] = zero4;
#pragma unroll
    for (int ni = 0; ni < 4; ++ni) {
      const u16* kp = Xk + base + (size_t)(k0 + ni * 16 + l15) * D_MODEL + hd + quad * 8;
      bf16x8 bk0 = *(const bf16x8*)(kp);
      bf16x8 bk1 = *(const bf16x8*)(kp + 32);
#pragma unroll
      for (int mi = 0; mi < 2; ++mi) {
        s[mi][ni] = __builtin_amdgcn_mfma_f32_16x16x32_bf16(aq[mi][0], bk0, s[mi][ni], 0, 0, 0);
        s[mi][ni] = __builtin_amdgcn_mfma_f32_16x16x32_bf16(aq[mi][1], bk1, s[mi][ni], 0, 0, 0);
      }
    }
#pragma unroll
    for (int mi = 0; mi < 2; ++mi)
#pragma unroll
      for (int ni = 0; ni < 4; ++ni)
#pragma unroll
        for (int r = 0; r < 4; ++r)
          Ss[(w * 32 + mi * 16 + quad * 4 + r) * 65 + ni * 16 + l15] = s[mi][ni][r];
    __syncthreads();

    // online softmax: thread t owns row t (threads 0..127)
    if (tid < 128) {
      const int qa = q0 + tid;
      int nv = qa - k0 + 1; nv = nv > 64 ? 64 : nv;   // valid keys in this tile
      if (nv <= 0) {
        al[tid] = 1.f;
        uint4 z = make_uint4(0u, 0u, 0u, 0u);
#pragma unroll
        for (int jb = 0; jb < 8; ++jb) *(uint4*)(Ps + tid * 72 + jb * 8) = z;
      } else {
        const float* srow = Ss + tid * 65;
        float mx = -1e30f;
        for (int j = 0; j < nv; ++j) mx = fmaxf(mx, srow[j]);
        mx *= 0.125f;                                  // 1/sqrt(64), exact
        float mnew = fmaxf(m_r, mx);
        float a = __expf(m_r - mnew);
        float sum = 0.f;
#pragma unroll
        for (int jb = 0; jb < 8; ++jb) {
          float p[8];
#pragma unroll
          for (int u = 0; u < 8; ++u) {
            int j = jb * 8 + u;
            float pv = 0.f;
            if (j < nv) { pv = __expf(srow[j] * 0.125f - mnew); sum += pv; }
            p[u] = pv;
          }
          uint4 pk;
          pk.x = pack2(p[0], p[1]); pk.y = pack2(p[2], p[3]);
          pk.z = pack2(p[4], p[5]); pk.w = pack2(p[6], p[7]);
          *(uint4*)(Ps + tid * 72 + jb * 8) = pk;
        }
        m_r = mnew; l_r = l_r * a + sum; al[tid] = a;
      }
    }
    __syncthreads();

    // rescale O, then O += P V
#pragma unroll
    for (int mi = 0; mi < 2; ++mi) {
      f32x4 av = *(const f32x4*)(al + w * 32 + mi * 16 + quad * 4);
#pragma unroll
      for (int di = 0; di < 4; ++di)
#pragma unroll
        for (int r = 0; r < 4; ++r) o[mi][di][r] *= av[r];
    }
#pragma unroll
    for (int js = 0; js < 2; ++js) {
      bf16x8 ap[2], bv[4];
#pragma unroll
      for (int mi = 0; mi < 2; ++mi)
        ap[mi] = *(const bf16x8*)(Ps + (w * 32 + mi * 16 + l15) * 72 + js * 32 + quad * 8);
#pragma unroll
      for (int di = 0; di < 4; ++di)
        bv[di] = *(const bf16x8*)(Vt + (di * 16 + l15) * 72 + js * 32 + quad * 8);
#pragma unroll
      for (int mi = 0; mi < 2; ++mi)
#pragma unroll
        for (int di = 0; di < 4; ++di)
          o[mi][di] = __builtin_amdgcn_mfma_f32_16x16x32_bf16(ap[mi], bv[di], o[mi][di], 0, 0, 0);
    }
  }

  __syncthreads();
  if (tid < 128) al[tid] = 1.f / l_r;
  __syncthreads();
#pragma unroll
  for (int mi = 0; mi < 2; ++mi) {
    f32x4 iv = *(const f32x4*)(al + w * 32 + mi * 16 + quad * 4);
#pragma unroll
    for (int di = 0; di < 4; ++di)
#pragma unroll
      for (int r = 0; r < 4; ++r)
        O[base + (size_t)(q0 + w * 32 + mi * 16 + quad * 4 + r) * D_MODEL + hd + di * 16 + l15]
          = f2bf(o[mi][di][r] * iv[r]);
  }
}

// ---------------- launch ----------------
extern "C" void kernel_launch(void* const* d_in, const int* in_sizes, int n_in,
                              void* d_out, int out_size, void* d_ws, size_t ws_size,
                              hipStream_t stream) {
  const float* q   = (const float*)d_in[0];
  const float* k   = (const float*)d_in[1];
  const float* v   = (const float*)d_in[2];
  // d_in[3] = causal mask, known tril -> ignored
  const float* w_q = (const float*)d_in[4];  const float* b_q = (const float*)d_in[5];
  const float* w_k = (const float*)d_in[6];  const float* b_k = (const float*)d_in[7];
  const float* w_v = (const float*)d_in[8];  const float* b_v = (const float*)d_in[9];
  const float* w_o = (const float*)d_in[10]; const float* b_o = (const float*)d_in[11];

  u16* ws = (u16*)d_ws;
  const size_t NTD = (size_t)NB * T_SEQ * D_MODEL;   // 8388608 elems
  const size_t WSZ = (size_t)D_MODEL * D_MODEL;      // 1048576 elems
  u16* wqb = ws;
  u16* wkb = wqb + WSZ;
  u16* wvb = wkb + WSZ;
  u16* wob = wvb + WSZ;
  u16* Xq  = wob + WSZ;
  u16* Xk  = Xq + NTD;
  u16* Xv  = Xk + NTD;
  u16* Ob  = Xv + NTD;
  // total ws use: 4*2MB + 4*16.78MB = 75.5 MB

  cast_f32_bf16<<<WSZ / 1024, 256, 0, stream>>>(w_q, wqb, (int)WSZ);
  cast_f32_bf16<<<WSZ / 1024, 256, 0, stream>>>(w_k, wkb, (int)WSZ);
  cast_f32_bf16<<<WSZ / 1024, 256, 0, stream>>>(w_v, wvb, (int)WSZ);
  cast_f32_bf16<<<WSZ / 1024, 256, 0, stream>>>(w_o, wob, (int)WSZ);

  dim3 g(64, 8, 1);
  gemm_nt<1, 1><<<g, 256, 0, stream>>>(q, wqb, b_q, Xq, 8192, 1024, 1024);
  gemm_nt<1, 1><<<g, 256, 0, stream>>>(k, wkb, b_k, Xk, 8192, 1024, 1024);
  gemm_nt<1, 1><<<g, 256, 0, stream>>>(v, wvb, b_v, Xv, 8192, 1024, 1024);

  attn_fwd<<<dim3(16, NH, NB), 256, 0, stream>>>(Xq, Xk, Xv, Ob);

  gemm_nt<0, 0><<<g, 256, 0, stream>>>(Ob, wob, b_o, d_out, 8192, 1024, 1024);
}

// Round 2
// 638.362 us; speedup vs baseline: 1.6044x; 1.6044x over previous
//
#include <hip/hip_runtime.h>

typedef unsigned short u16;
typedef __attribute__((ext_vector_type(8))) short bf16x8;
typedef __attribute__((ext_vector_type(4))) float f32x4;

#define D_MODEL 1024
#define T_SEQ   2048
#define NB      4
#define NH      16
#define DKH     64

__device__ __forceinline__ u16 f2bf(float x) {
  union { float f; unsigned u; } v; v.f = x;
  unsigned r = v.u + 0x7fffu + ((v.u >> 16) & 1u);
  return (u16)(r >> 16);
}
__device__ __forceinline__ unsigned pack2(float a, float b) {
  return (unsigned)f2bf(a) | ((unsigned)f2bf(b) << 16);
}

// ---------------- cast 4 weight matrices fp32 -> bf16 in one launch ----------------
__global__ void cast_w4(const float* __restrict__ s0, const float* __restrict__ s1,
                        const float* __restrict__ s2, const float* __restrict__ s3,
                        u16* __restrict__ o0, u16* __restrict__ o1,
                        u16* __restrict__ o2, u16* __restrict__ o3) {
  const int which = blockIdx.y;
  const float* s = which == 0 ? s0 : which == 1 ? s1 : which == 2 ? s2 : s3;
  u16* o = which == 0 ? o0 : which == 1 ? o1 : which == 2 ? o2 : o3;
  int i = ((int)blockIdx.x * 256 + (int)threadIdx.x) * 4;
  float4 v = *(const float4*)(s + i);
  uint2 u; u.x = pack2(v.x, v.y); u.y = pack2(v.z, v.w);
  *(uint2*)(o + i) = u;
}

// ---------------- GEMM: C[M,N] = A[M,K] @ W[N,K]^T + bias ----------------
#define LDSK 72   // padded LDS row stride (bf16 elems)

template<int OUT_BF16, int A_F32>
__global__ __launch_bounds__(256) void gemm_nt(const void* __restrict__ Ap,
                                               const u16* __restrict__ W,
                                               const float* __restrict__ bias,
                                               void* __restrict__ Cp,
                                               int M, int N, int K) {
  __shared__ __align__(16) u16 As[128 * LDSK];
  __shared__ __align__(16) u16 Bs[128 * LDSK];
  const int tid = threadIdx.x;
  const int w = tid >> 6, lane = tid & 63;
  const int wm = w & 1, wn = w >> 1;
  const int l15 = lane & 15, quad = lane >> 4;
  const int m0 = blockIdx.x * 128, n0 = blockIdx.y * 128;
  const int srow = tid >> 3;
  const int scol = (tid & 7) * 8;

  f32x4 zero4 = {0.f, 0.f, 0.f, 0.f};
  f32x4 acc[4][4];
#pragma unroll
  for (int i = 0; i < 4; ++i)
#pragma unroll
    for (int j = 0; j < 4; ++j) acc[i][j] = zero4;

  for (int kb = 0; kb < K; kb += 64) {
    uint4 ra[4], rb[4];
    if (A_F32) {
      const float* Af = (const float*)Ap;
#pragma unroll
      for (int r = 0; r < 4; ++r) {
        const float* p = Af + (size_t)(m0 + r * 32 + srow) * K + kb + scol;
        float4 x = *(const float4*)p;
        float4 y = *(const float4*)(p + 4);
        ra[r].x = pack2(x.x, x.y); ra[r].y = pack2(x.z, x.w);
        ra[r].z = pack2(y.x, y.y); ra[r].w = pack2(y.z, y.w);
      }
    } else {
      const u16* Ab = (const u16*)Ap;
#pragma unroll
      for (int r = 0; r < 4; ++r)
        ra[r] = *(const uint4*)(Ab + (size_t)(m0 + r * 32 + srow) * K + kb + scol);
    }
#pragma unroll
    for (int r = 0; r < 4; ++r)
      rb[r] = *(const uint4*)(W + (size_t)(n0 + r * 32 + srow) * K + kb + scol);

    __syncthreads();
#pragma unroll
    for (int r = 0; r < 4; ++r) {
      *(uint4*)(As + (r * 32 + srow) * LDSK + scol) = ra[r];
      *(uint4*)(Bs + (r * 32 + srow) * LDSK + scol) = rb[r];
    }
    __syncthreads();

#pragma unroll
    for (int ks = 0; ks < 2; ++ks) {
      bf16x8 af[4], bfr[4];
#pragma unroll
      for (int i = 0; i < 4; ++i)
        af[i] = *(const bf16x8*)(As + (wm * 64 + i * 16 + l15) * LDSK + ks * 32 + quad * 8);
#pragma unroll
      for (int i = 0; i < 4; ++i)
        bfr[i] = *(const bf16x8*)(Bs + (wn * 64 + i * 16 + l15) * LDSK + ks * 32 + quad * 8);
#pragma unroll
      for (int mi = 0; mi < 4; ++mi)
#pragma unroll
        for (int ni = 0; ni < 4; ++ni)
          acc[mi][ni] = __builtin_amdgcn_mfma_f32_16x16x32_bf16(af[mi], bfr[ni], acc[mi][ni], 0, 0, 0);
    }
  }

#pragma unroll
  for (int ni = 0; ni < 4; ++ni) {
    int col = n0 + wn * 64 + ni * 16 + l15;
    float bv = bias[col];
#pragma unroll
    for (int mi = 0; mi < 4; ++mi) {
      int row = m0 + wm * 64 + mi * 16 + quad * 4;
#pragma unroll
      for (int r = 0; r < 4; ++r) {
        float vv = acc[mi][ni][r] + bv;
        if (OUT_BF16) ((u16*)Cp)[(size_t)(row + r) * N + col] = f2bf(vv);
        else          ((float*)Cp)[(size_t)(row + r) * N + col] = vv;
      }
    }
  }
}

// ---------------- causal flash attention, in-register online softmax ----------------
// grid: (16 [reversed], NH, NB); block 256 (4 waves). Q-tile 128 (32/wave), K-tile 64.
__global__ __launch_bounds__(256) void attn_fwd(const u16* __restrict__ Xq,
                                                const u16* __restrict__ Xk,
                                                const u16* __restrict__ Xv,
                                                u16* __restrict__ O) {
  __shared__ __align__(16) u16 Ps[128 * 72];  // P bf16 [q][key]
  __shared__ __align__(16) u16 Vt[64 * 72];   // V^T bf16 [d][key]

  const int qt = (int)gridDim.x - 1 - (int)blockIdx.x;  // heavy tiles first
  const int h = blockIdx.y, b = blockIdx.z;
  const int tid = threadIdx.x;
  const int w = tid >> 6, lane = tid & 63;
  const int l15 = lane & 15, quad = lane >> 4;
  const size_t base = (size_t)b * T_SEQ * D_MODEL;
  const int q0 = qt * 128;
  const int hd = h * DKH;
  const int rowb0 = q0 + w * 32;

  // Q fragments (A-operand layout), held in registers all kernel
  bf16x8 aq[2][2];
#pragma unroll
  for (int mi = 0; mi < 2; ++mi)
#pragma unroll
    for (int ks = 0; ks < 2; ++ks)
      aq[mi][ks] = *(const bf16x8*)(Xq + base + (size_t)(rowb0 + mi * 16 + l15) * D_MODEL
                                    + hd + ks * 32 + quad * 8);

  // all-ones B fragment: extra MFMA column computes running row-sum l
  bf16x8 bones;
#pragma unroll
  for (int i = 0; i < 8; ++i) bones[i] = (short)0x3F80;  // bf16 1.0

  f32x4 zero4 = {0.f, 0.f, 0.f, 0.f};
  f32x4 o[2][4], ol[2];
#pragma unroll
  for (int i = 0; i < 2; ++i) {
    ol[i] = zero4;
#pragma unroll
    for (int j = 0; j < 4; ++j) o[i][j] = zero4;
  }
  float m_s[2][4];
#pragma unroll
  for (int i = 0; i < 2; ++i)
#pragma unroll
    for (int r = 0; r < 4; ++r) m_s[i][r] = -1e30f;

  const int vkey = tid & 63, vdp = tid >> 6;   // V staging: thread owns 1 key, 16 dims
  const int nkt = 2 * qt + 2;

  for (int kt = 0; kt < nkt; ++kt) {
    const int k0 = kt * 64;

    // global loads first (overlap with barrier wait)
    const u16* vp = Xv + base + (size_t)(k0 + vkey) * D_MODEL + hd + vdp * 16;
    uint4 va0 = *(const uint4*)vp;
    uint4 va1 = *(const uint4*)(vp + 8);

    bf16x8 bk[4][2];
#pragma unroll
    for (int ni = 0; ni < 4; ++ni) {
      const u16* kp = Xk + base + (size_t)(k0 + ni * 16 + l15) * D_MODEL + hd + quad * 8;
      bk[ni][0] = *(const bf16x8*)kp;
      bk[ni][1] = *(const bf16x8*)(kp + 32);
    }

    __syncthreads();   // prev iteration's Ps/Vt reads complete

    // stage V^T (conflict-free: per inst, lanes span 64 consecutive keys)
    {
      union { uint4 u; u16 h[8]; } u0, u1;
      u0.u = va0; u1.u = va1;
#pragma unroll
      for (int i = 0; i < 8; ++i) {
        Vt[(vdp * 16 + i) * 72 + vkey] = u0.h[i];
        Vt[(vdp * 16 + 8 + i) * 72 + vkey] = u1.h[i];
      }
    }

    // S = Q K^T in registers
    f32x4 s[2][4];
#pragma unroll
    for (int i = 0; i < 2; ++i)
#pragma unroll
      for (int j = 0; j < 4; ++j) s[i][j] = zero4;
#pragma unroll
    for (int ni = 0; ni < 4; ++ni)
#pragma unroll
      for (int mi = 0; mi < 2; ++mi) {
        s[mi][ni] = __builtin_amdgcn_mfma_f32_16x16x32_bf16(aq[mi][0], bk[ni][0], s[mi][ni], 0, 0, 0);
        s[mi][ni] = __builtin_amdgcn_mfma_f32_16x16x32_bf16(aq[mi][1], bk[ni][1], s[mi][ni], 0, 0, 0);
      }

    // causal mask + online softmax, all in registers
#pragma unroll
    for (int mi = 0; mi < 2; ++mi) {
      const int rb = rowb0 + mi * 16 + quad * 4;   // row = rb + r
      if (k0 + 63 > rowb0 + mi * 16) {             // wave-uniform: diagonal tile
#pragma unroll
        for (int ni = 0; ni < 4; ++ni) {
          const int colb = k0 + ni * 16 + l15;
#pragma unroll
          for (int r = 0; r < 4; ++r)
            if (colb > rb + r) s[mi][ni][r] = -1e30f;
        }
      }
      // row max: in-lane over ni, then shuffle over the 16 lanes sharing quad
      float mx[4];
#pragma unroll
      for (int r = 0; r < 4; ++r)
        mx[r] = fmaxf(fmaxf(s[mi][0][r], s[mi][1][r]), fmaxf(s[mi][2][r], s[mi][3][r]));
#pragma unroll
      for (int d = 1; d <= 8; d <<= 1)
#pragma unroll
        for (int r = 0; r < 4; ++r)
          mx[r] = fmaxf(mx[r], __shfl_xor(mx[r], d));

#pragma unroll
      for (int r = 0; r < 4; ++r) {
        float msc = mx[r] * 0.125f;                 // 1/sqrt(64)
        float mnew = fmaxf(m_s[mi][r], msc);
        float a = __expf(m_s[mi][r] - mnew);
        m_s[mi][r] = mnew;
        ol[mi][r] *= a;
#pragma unroll
        for (int di = 0; di < 4; ++di) o[mi][di][r] *= a;
        u16* pr = Ps + (w * 32 + mi * 16 + quad * 4 + r) * 72 + l15;
#pragma unroll
        for (int ni = 0; ni < 4; ++ni) {
          float pv = __expf(s[mi][ni][r] * 0.125f - mnew);
          pr[ni * 16] = f2bf(pv);
        }
      }
    }
    __syncthreads();   // Ps / Vt visible

    // O += P V ; ol += P 1 (running softmax denominator, rescales with O)
#pragma unroll
    for (int js = 0; js < 2; ++js) {
      bf16x8 ap[2], bv[4];
#pragma unroll
      for (int mi = 0; mi < 2; ++mi)
        ap[mi] = *(const bf16x8*)(Ps + (w * 32 + mi * 16 + l15) * 72 + js * 32 + quad * 8);
#pragma unroll
      for (int di = 0; di < 4; ++di)
        bv[di] = *(const bf16x8*)(Vt + (di * 16 + l15) * 72 + js * 32 + quad * 8);
#pragma unroll
      for (int mi = 0; mi < 2; ++mi) {
#pragma unroll
        for (int di = 0; di < 4; ++di)
          o[mi][di] = __builtin_amdgcn_mfma_f32_16x16x32_bf16(ap[mi], bv[di], o[mi][di], 0, 0, 0);
        ol[mi] = __builtin_amdgcn_mfma_f32_16x16x32_bf16(ap[mi], bones, ol[mi], 0, 0, 0);
      }
    }
  }

  // epilogue: normalize by the MFMA-accumulated row sums
#pragma unroll
  for (int mi = 0; mi < 2; ++mi) {
    float inv[4];
#pragma unroll
    for (int r = 0; r < 4; ++r) inv[r] = 1.0f / ol[mi][r];
#pragma unroll
    for (int di = 0; di < 4; ++di)
#pragma unroll
      for (int r = 0; r < 4; ++r)
        O[base + (size_t)(rowb0 + mi * 16 + quad * 4 + r) * D_MODEL + hd + di * 16 + l15]
          = f2bf(o[mi][di][r] * inv[r]);
  }
}

// ---------------- launch ----------------
extern "C" void kernel_launch(void* const* d_in, const int* in_sizes, int n_in,
                              void* d_out, int out_size, void* d_ws, size_t ws_size,
                              hipStream_t stream) {
  const float* q   = (const float*)d_in[0];
  const float* k   = (const float*)d_in[1];
  const float* v   = (const float*)d_in[2];
  const float* w_q = (const float*)d_in[4];  const float* b_q = (const float*)d_in[5];
  const float* w_k = (const float*)d_in[6];  const float* b_k = (const float*)d_in[7];
  const float* w_v = (const float*)d_in[8];  const float* b_v = (const float*)d_in[9];
  const float* w_o = (const float*)d_in[10]; const float* b_o = (const float*)d_in[11];

  u16* ws = (u16*)d_ws;
  const size_t NTD = (size_t)NB * T_SEQ * D_MODEL;
  const size_t WSZ = (size_t)D_MODEL * D_MODEL;
  u16* wqb = ws;
  u16* wkb = wqb + WSZ;
  u16* wvb = wkb + WSZ;
  u16* wob = wvb + WSZ;
  u16* Xq  = wob + WSZ;
  u16* Xk  = Xq + NTD;
  u16* Xv  = Xk + NTD;
  u16* Ob  = Xv + NTD;

  cast_w4<<<dim3(WSZ / 1024, 4), 256, 0, stream>>>(w_q, w_k, w_v, w_o, wqb, wkb, wvb, wob);

  dim3 g(64, 8, 1);
  gemm_nt<1, 1><<<g, 256, 0, stream>>>(q, wqb, b_q, Xq, 8192, 1024, 1024);
  gemm_nt<1, 1><<<g, 256, 0, stream>>>(k, wkb, b_k, Xk, 8192, 1024, 1024);
  gemm_nt<1, 1><<<g, 256, 0, stream>>>(v, wvb, b_v, Xv, 8192, 1024, 1024);

  attn_fwd<<<dim3(16, NH, NB), 256, 0, stream>>>(Xq, Xk, Xv, Ob);

  gemm_nt<0, 0><<<g, 256, 0, stream>>>(Ob, wob, b_o, d_out, 8192, 1024, 1024);
}

// Round 3
// 371.113 us; speedup vs baseline: 2.7598x; 1.7201x over previous
//
#include <hip/hip_runtime.h>

typedef unsigned short u16;
typedef __attribute__((ext_vector_type(8))) short bf16x8;
typedef __attribute__((ext_vector_type(4))) float f32x4;

#define D_MODEL 1024
#define T_SEQ   2048
#define NB      4
#define NH      16
#define DKH     64

__device__ __forceinline__ u16 f2bf(float x) {
  union { float f; unsigned u; } v; v.f = x;
  unsigned r = v.u + 0x7fffu + ((v.u >> 16) & 1u);
  return (u16)(r >> 16);
}
__device__ __forceinline__ unsigned pack2(float a, float b) {
  return (unsigned)f2bf(a) | ((unsigned)f2bf(b) << 16);
}

// async global->LDS, 16B per lane. LDS dest = wave-uniform base + lane*16.
__device__ __forceinline__ void gload16(const void* g, void* l) {
  __builtin_amdgcn_global_load_lds(
      (const __attribute__((address_space(1))) unsigned*)g,
      (__attribute__((address_space(3))) unsigned*)l, 16, 0, 0);
}

// ---------------- cast 4 weight matrices fp32 -> bf16 ----------------
__global__ void cast_w4(const float* __restrict__ s0, const float* __restrict__ s1,
                        const float* __restrict__ s2, const float* __restrict__ s3,
                        u16* __restrict__ o0, u16* __restrict__ o1,
                        u16* __restrict__ o2, u16* __restrict__ o3) {
  const int which = blockIdx.y;
  const float* s = which == 0 ? s0 : which == 1 ? s1 : which == 2 ? s2 : s3;
  u16* o = which == 0 ? o0 : which == 1 ? o1 : which == 2 ? o2 : o3;
  int i = ((int)blockIdx.x * 256 + (int)threadIdx.x) * 4;
  float4 v = *(const float4*)(s + i);
  uint2 u; u.x = pack2(v.x, v.y); u.y = pack2(v.z, v.w);
  *(uint2*)(o + i) = u;
}

// ---------------- cast one fp32 tensor -> bf16 ----------------
__global__ void cast_x1(const float* __restrict__ s, u16* __restrict__ o) {
  size_t i = ((size_t)blockIdx.x * 256 + threadIdx.x) * 4;
  float4 v = *(const float4*)(s + i);
  uint2 u; u.x = pack2(v.x, v.y); u.y = pack2(v.z, v.w);
  *(uint2*)(o + i) = u;
}

// ---------------- GEMM: C[M,N] = A[M,K] @ W[N,K]^T + bias (bf16 in) ----------------
// 128x128 tile, BK=64, 4 waves. global_load_lds staging, XOR-swizzled LDS (stride 64).
// LDS slot s of row r holds global col-block s^(r&7)  (blocks of 8 bf16 = 16B).
template<int OUT_BF16>
__global__ __launch_bounds__(256) void gemm_nt(const u16* __restrict__ Ab,
                                               const u16* __restrict__ W,
                                               const float* __restrict__ bias,
                                               void* __restrict__ Cp,
                                               int M, int N, int K) {
  __shared__ __align__(16) u16 As[128 * 64];
  __shared__ __align__(16) u16 Bs[128 * 64];
  const int tid = threadIdx.x;
  const int w = tid >> 6, lane = tid & 63;
  const int wm = w & 1, wn = w >> 1;
  const int l15 = lane & 15, quad = lane >> 4;
  const int m0 = blockIdx.x * 128, n0 = blockIdx.y * 128;
  const int lrow = lane >> 3;                 // 0..7 within 8-row group
  const int lcol = ((lane & 7) ^ lrow) * 8;   // xor-swizzled source col block

  const u16* gA = Ab + (size_t)(m0 + w * 32 + lrow) * K + lcol;
  const u16* gB = W  + (size_t)(n0 + w * 32 + lrow) * K + lcol;
  u16* lA = As + w * 32 * 64;
  u16* lB = Bs + w * 32 * 64;

  f32x4 zero4 = {0.f, 0.f, 0.f, 0.f};
  f32x4 acc[4][4];
#pragma unroll
  for (int i = 0; i < 4; ++i)
#pragma unroll
    for (int j = 0; j < 4; ++j) acc[i][j] = zero4;

  for (int kb = 0; kb < K; kb += 64) {
    __syncthreads();   // prev iter's ds_reads done before overwrite
#pragma unroll
    for (int t = 0; t < 4; ++t) gload16(gA + kb + t * 8 * K, lA + t * 512);
#pragma unroll
    for (int t = 0; t < 4; ++t) gload16(gB + kb + t * 8 * K, lB + t * 512);
    __syncthreads();   // drains vmcnt -> LDS tiles ready

#pragma unroll
    for (int ks = 0; ks < 2; ++ks) {
      const int sA = (((ks * 4 + quad) ^ (l15 & 7)) * 8);
      bf16x8 af[4], bfr[4];
#pragma unroll
      for (int i = 0; i < 4; ++i)
        af[i] = *(const bf16x8*)(As + (wm * 64 + i * 16 + l15) * 64 + sA);
#pragma unroll
      for (int i = 0; i < 4; ++i)
        bfr[i] = *(const bf16x8*)(Bs + (wn * 64 + i * 16 + l15) * 64 + sA);
#pragma unroll
      for (int mi = 0; mi < 4; ++mi)
#pragma unroll
        for (int ni = 0; ni < 4; ++ni)
          acc[mi][ni] = __builtin_amdgcn_mfma_f32_16x16x32_bf16(af[mi], bfr[ni], acc[mi][ni], 0, 0, 0);
    }
  }

#pragma unroll
  for (int ni = 0; ni < 4; ++ni) {
    int col = n0 + wn * 64 + ni * 16 + l15;
    float bv = bias[col];
#pragma unroll
    for (int mi = 0; mi < 4; ++mi) {
      int row = m0 + wm * 64 + mi * 16 + quad * 4;
#pragma unroll
      for (int r = 0; r < 4; ++r) {
        float vv = acc[mi][ni][r] + bv;
        if (OUT_BF16) ((u16*)Cp)[(size_t)(row + r) * N + col] = f2bf(vv);
        else          ((float*)Cp)[(size_t)(row + r) * N + col] = vv;
      }
    }
  }
}

// ---------------- causal flash attention (transposed, zero-shuffle P) ----------------
// Computes S^T = K Q^T and O^T = V^T P^T. C-layout of S^T: lane l15 = q,
// rows quad*4+r = key. Custom K-slot permutation kappa(js,quad,j) =
// 32js+16(j>>2)+4quad+(j&3) makes the P^T B-fragment a pure in-lane repack;
// V is staged into LDS already kappa-permuted. One barrier/tile (Vt dbuf).
// Each block handles q-tile pair (15-x, x): uniform 36 k-tiles -> balanced.
__global__ __launch_bounds__(256) void attn_fwd(const u16* __restrict__ Xq,
                                                const u16* __restrict__ Xk,
                                                const u16* __restrict__ Xv,
                                                u16* __restrict__ O) {
  __shared__ __align__(16) u16 Vt[2][64 * 72];

  const int xp = blockIdx.x;                // 0..7
  const int h = blockIdx.y, b = blockIdx.z;
  const int tid = threadIdx.x;
  const int w = tid >> 6, lane = tid & 63;
  const int l15 = lane & 15, quad = lane >> 4;
  const size_t base = (size_t)b * T_SEQ * D_MODEL;
  const int hd = h * DKH;
  const int vkey = tid & 63, vdp = tid >> 6;
  // kappa-permuted slot for this thread's key
  const int skey = (vkey & 0x20) | ((vkey & 0xC) << 1) | ((vkey & 0x10) >> 2) | (vkey & 3);

  bf16x8 bones;
#pragma unroll
  for (int i = 0; i < 8; ++i) bones[i] = (short)0x3F80;  // bf16 1.0

  f32x4 zero4 = {0.f, 0.f, 0.f, 0.f};
  int tcnt = 0;

  for (int ph = 0; ph < 2; ++ph) {
    const int qt = ph ? xp : 15 - xp;       // heavy tile first
    const int q0 = qt * 128;
    const int rowb0 = q0 + w * 32;

    bf16x8 bq[2][2];
#pragma unroll
    for (int mi = 0; mi < 2; ++mi)
#pragma unroll
      for (int ks = 0; ks < 2; ++ks)
        bq[mi][ks] = *(const bf16x8*)(Xq + base + (size_t)(rowb0 + mi * 16 + l15) * D_MODEL
                                      + hd + ks * 32 + quad * 8);

    f32x4 o[4][2], ol[2];
#pragma unroll
    for (int di = 0; di < 4; ++di)
#pragma unroll
      for (int mi = 0; mi < 2; ++mi) o[di][mi] = zero4;
#pragma unroll
    for (int mi = 0; mi < 2; ++mi) ol[mi] = zero4;
    float m_s[2] = {-1e30f, -1e30f};

    const int nkt = 2 * qt + 2;
    for (int kt = 0; kt < nkt; ++kt, ++tcnt) {
      const int k0 = kt * 64;
      const int buf = tcnt & 1;

      // V tile global loads (issued early)
      const u16* vp = Xv + base + (size_t)(k0 + vkey) * D_MODEL + hd + vdp * 16;
      uint4 va0 = *(const uint4*)vp;
      uint4 va1 = *(const uint4*)(vp + 8);

      // K A-fragments straight from global (L2-resident)
      bf16x8 ak[4][2];
#pragma unroll
      for (int ni = 0; ni < 4; ++ni) {
        const u16* kp = Xk + base + (size_t)(k0 + ni * 16 + l15) * D_MODEL + hd + quad * 8;
        ak[ni][0] = *(const bf16x8*)kp;
        ak[ni][1] = *(const bf16x8*)(kp + 32);
      }

      // stage V^T kappa-permuted into Vt[buf]
      {
        union { uint4 u; u16 hh[8]; } u0, u1;
        u0.u = va0; u1.u = va1;
        u16* vtb = Vt[buf];
#pragma unroll
        for (int i = 0; i < 8; ++i) {
          vtb[(vdp * 16 + i) * 72 + skey] = u0.hh[i];
          vtb[(vdp * 16 + 8 + i) * 72 + skey] = u1.hh[i];
        }
      }

      // S^T = K Q^T
      f32x4 st[4][2];
#pragma unroll
      for (int ni = 0; ni < 4; ++ni)
#pragma unroll
        for (int mi = 0; mi < 2; ++mi) {
          f32x4 t = zero4;
          t = __builtin_amdgcn_mfma_f32_16x16x32_bf16(ak[ni][0], bq[mi][0], t, 0, 0, 0);
          t = __builtin_amdgcn_mfma_f32_16x16x32_bf16(ak[ni][1], bq[mi][1], t, 0, 0, 0);
          st[ni][mi] = t;
        }

      // mask + online softmax + in-lane pack to B-layout (kappa order)
      bf16x8 bp[2][2];
#pragma unroll
      for (int mi = 0; mi < 2; ++mi) {
        const int qa = rowb0 + mi * 16 + l15;
        if (k0 + 63 > rowb0 + mi * 16) {
#pragma unroll
          for (int ni = 0; ni < 4; ++ni)
#pragma unroll
            for (int r = 0; r < 4; ++r)
              if (k0 + ni * 16 + quad * 4 + r > qa) st[ni][mi][r] = -1e30f;
        }
        float mx = st[0][mi][0];
#pragma unroll
        for (int ni = 0; ni < 4; ++ni)
#pragma unroll
          for (int r = 0; r < 4; ++r) mx = fmaxf(mx, st[ni][mi][r]);
        mx = fmaxf(mx, __shfl_xor(mx, 16));
        mx = fmaxf(mx, __shfl_xor(mx, 32));
        float mnew = fmaxf(m_s[mi], mx * 0.125f);
        float a = __expf(m_s[mi] - mnew);
        m_s[mi] = mnew;
#pragma unroll
        for (int r = 0; r < 4; ++r) ol[mi][r] *= a;
#pragma unroll
        for (int di = 0; di < 4; ++di)
#pragma unroll
          for (int r = 0; r < 4; ++r) o[di][mi][r] *= a;

        float p[4][4];
#pragma unroll
        for (int ni = 0; ni < 4; ++ni)
#pragma unroll
          for (int r = 0; r < 4; ++r)
            p[ni][r] = __expf(st[ni][mi][r] * 0.125f - mnew);
#pragma unroll
        for (int js = 0; js < 2; ++js) {
          union { bf16x8 v; unsigned d[4]; } ub;
          ub.d[0] = pack2(p[2 * js][0], p[2 * js][1]);
          ub.d[1] = pack2(p[2 * js][2], p[2 * js][3]);
          ub.d[2] = pack2(p[2 * js + 1][0], p[2 * js + 1][1]);
          ub.d[3] = pack2(p[2 * js + 1][2], p[2 * js + 1][3]);
          bp[mi][js] = ub.v;
        }
      }

      __syncthreads();   // Vt[buf] fully written (single barrier per tile)

      // O^T += V^T P^T ; ol += 1 P^T
#pragma unroll
      for (int js = 0; js < 2; ++js) {
        bf16x8 av[4];
#pragma unroll
        for (int di = 0; di < 4; ++di)
          av[di] = *(const bf16x8*)(Vt[buf] + (di * 16 + l15) * 72 + js * 32 + quad * 8);
#pragma unroll
        for (int di = 0; di < 4; ++di)
#pragma unroll
          for (int mi = 0; mi < 2; ++mi)
            o[di][mi] = __builtin_amdgcn_mfma_f32_16x16x32_bf16(av[di], bp[mi][js], o[di][mi], 0, 0, 0);
#pragma unroll
        for (int mi = 0; mi < 2; ++mi)
          ol[mi] = __builtin_amdgcn_mfma_f32_16x16x32_bf16(bones, bp[mi][js], ol[mi], 0, 0, 0);
      }
    }

    // epilogue: O^T C-layout -> row-major O, packed 8B stores
#pragma unroll
    for (int mi = 0; mi < 2; ++mi) {
      float inv = 1.0f / ol[mi][0];
      const size_t qa = rowb0 + mi * 16 + l15;
#pragma unroll
      for (int di = 0; di < 4; ++di) {
        uint2 s2;
        s2.x = pack2(o[di][mi][0] * inv, o[di][mi][1] * inv);
        s2.y = pack2(o[di][mi][2] * inv, o[di][mi][3] * inv);
        *(uint2*)(O + base + qa * D_MODEL + hd + di * 16 + quad * 4) = s2;
      }
    }
  }
}

// ---------------- launch ----------------
extern "C" void kernel_launch(void* const* d_in, const int* in_sizes, int n_in,
                              void* d_out, int out_size, void* d_ws, size_t ws_size,
                              hipStream_t stream) {
  const float* q   = (const float*)d_in[0];
  const float* k   = (const float*)d_in[1];
  const float* v   = (const float*)d_in[2];
  const float* w_q = (const float*)d_in[4];  const float* b_q = (const float*)d_in[5];
  const float* w_k = (const float*)d_in[6];  const float* b_k = (const float*)d_in[7];
  const float* w_v = (const float*)d_in[8];  const float* b_v = (const float*)d_in[9];
  const float* w_o = (const float*)d_in[10]; const float* b_o = (const float*)d_in[11];

  u16* ws = (u16*)d_ws;
  const size_t NTD = (size_t)NB * T_SEQ * D_MODEL;   // 8388608
  const size_t WSZ = (size_t)D_MODEL * D_MODEL;      // 1048576
  u16* wqb = ws;
  u16* wkb = wqb + WSZ;
  u16* wvb = wkb + WSZ;
  u16* wob = wvb + WSZ;
  u16* Xq  = wob + WSZ;
  u16* Xk  = Xq + NTD;
  u16* Xv  = Xk + NTD;
  u16* Cb  = Xv + NTD;   // cast buffer, later reused as attention output Ob
  // total ws: 4*2MB + 4*16.78MB = 75.5 MB (same as round 1)

  cast_w4<<<dim3(WSZ / 1024, 4), 256, 0, stream>>>(w_q, w_k, w_v, w_o, wqb, wkb, wvb, wob);

  dim3 g(64, 8, 1);
  cast_x1<<<NTD / 1024, 256, 0, stream>>>(q, Cb);
  gemm_nt<1><<<g, 256, 0, stream>>>(Cb, wqb, b_q, Xq, 8192, 1024, 1024);
  cast_x1<<<NTD / 1024, 256, 0, stream>>>(k, Cb);
  gemm_nt<1><<<g, 256, 0, stream>>>(Cb, wkb, b_k, Xk, 8192, 1024, 1024);
  cast_x1<<<NTD / 1024, 256, 0, stream>>>(v, Cb);
  gemm_nt<1><<<g, 256, 0, stream>>>(Cb, wvb, b_v, Xv, 8192, 1024, 1024);

  attn_fwd<<<dim3(8, NH, NB), 256, 0, stream>>>(Xq, Xk, Xv, Cb);

  gemm_nt<0><<<g, 256, 0, stream>>>(Cb, wob, b_o, d_out, 8192, 1024, 1024);
}